// Round 1
// baseline (325.030 us; speedup 1.0000x reference)
//
#include <hip/hip_runtime.h>

// ---------------------------------------------------------------------------
// MultiheadAttentionWithAttention: y = Wo(attn(Wq q, Wk k, Wv v)) + bo,
// plus head-mean attention map. B=4, T=T_MEM=1024, C=1024, H=16, hd=64.
//
// Pipeline (all bf16 MFMA, fp32 accum):
//   1. convert inputs + weights fp32->bf16 (Wq,bq pre-scaled by 1/8)
//   2. QKV projections: one batched 128x128-tile gemm_bt (grid.z = q/k/v)
//   3. transpose V to [b,h,d,t] for contiguous-k PV fragments
//   4. fused attention: block = (b, 16 q-rows), loops all 16 heads;
//      scores in LDS (bf16, stride 1032), exact softmax, head-mean
//      accumulated in registers, written once (no atomics)
//   5. output projection -> fp32 d_out
//
// ws layout (MB): [0,24) x_in bf16 (q,k,v) | [24,32) W bf16 (q,k,v,o)
//                 [32,56) Qp,Kp,Vp | Vt reuses [8,16) | Ybf reuses [16,24)
// ---------------------------------------------------------------------------

typedef __attribute__((ext_vector_type(8))) short s16x8;
typedef __attribute__((ext_vector_type(4))) float f32x4;
typedef __attribute__((ext_vector_type(4))) unsigned short u16x4;

#define N_EMBD 1024
#define NH 16
#define BT 4096  // B*T flattened rows

static __device__ __forceinline__ unsigned short f2bf(float f) {
  unsigned int u = __builtin_bit_cast(unsigned int, f);
  u += 0x7FFFu + ((u >> 16) & 1u);  // RNE
  return (unsigned short)(u >> 16);
}
static __device__ __forceinline__ float bf2f(unsigned short h) {
  return __builtin_bit_cast(float, ((unsigned int)h) << 16);
}

// ---------------- fp32 -> bf16 convert (optional scale) ----------------
__global__ __launch_bounds__(256) void cvt_f32_bf16(const float* __restrict__ in,
                                                    unsigned short* __restrict__ out,
                                                    int n, float scale) {
  int i = (blockIdx.x * 256 + threadIdx.x) * 4;
  if (i < n) {
    float4 v = *(const float4*)(in + i);
    u16x4 o;
    o[0] = f2bf(v.x * scale);
    o[1] = f2bf(v.y * scale);
    o[2] = f2bf(v.z * scale);
    o[3] = f2bf(v.w * scale);
    *(u16x4*)(out + i) = o;
  }
}

// ---------------- 128x128 bf16 MFMA tile: C = A * B^T + bias ----------------
// A [M,K], B [N,K] row-major bf16. Verified gemm_bt fragment pattern:
// A/B frag: lane reads row (l&15), k = 32*kf + 8*(l>>4), 8 contiguous bf16.
// D frag:   row = (l>>4)*4 + r, col = l&15.
template <bool F32OUT>
static __device__ __forceinline__ void gemm_bt_tile(const unsigned short* __restrict__ A,
                                                    const unsigned short* __restrict__ B,
                                                    const float* __restrict__ bias, float bscale,
                                                    void* __restrict__ Cout,
                                                    int m0, int n0, int N, int K,
                                                    unsigned short* Al, unsigned short* Bl) {
  const int tid = threadIdx.x;
  const int l = tid & 63, w = tid >> 6;
  const int wr = w >> 1, wc = w & 1;
  const int l15 = l & 15, l4 = l >> 4;
  const int srow = tid >> 3;          // staging row within 32-row chunk
  const int skk = (tid & 7) * 8;      // staging k offset (16B)
  f32x4 acc[4][4] = {};
  for (int k0 = 0; k0 < K; k0 += 64) {
#pragma unroll
    for (int i = 0; i < 4; ++i) {
      int row = i * 32 + srow;
      *(s16x8*)&Al[row * 64 + skk] = *(const s16x8*)&A[(size_t)(m0 + row) * K + k0 + skk];
      *(s16x8*)&Bl[row * 64 + skk] = *(const s16x8*)&B[(size_t)(n0 + row) * K + k0 + skk];
    }
    __syncthreads();
#pragma unroll
    for (int kf = 0; kf < 2; ++kf) {
      s16x8 af[4], bfr[4];
#pragma unroll
      for (int mi = 0; mi < 4; ++mi)
        af[mi] = *(const s16x8*)&Al[(wr * 64 + mi * 16 + l15) * 64 + kf * 32 + l4 * 8];
#pragma unroll
      for (int nj = 0; nj < 4; ++nj)
        bfr[nj] = *(const s16x8*)&Bl[(wc * 64 + nj * 16 + l15) * 64 + kf * 32 + l4 * 8];
#pragma unroll
      for (int mi = 0; mi < 4; ++mi) {
#pragma unroll
        for (int nj = 0; nj < 4; ++nj)
          acc[mi][nj] =
              __builtin_amdgcn_mfma_f32_16x16x32_bf16(af[mi], bfr[nj], acc[mi][nj], 0, 0, 0);
      }
    }
    __syncthreads();
  }
#pragma unroll
  for (int nj = 0; nj < 4; ++nj) {
    int col = n0 + wc * 64 + nj * 16 + l15;
    float bv = bias[col] * bscale;
#pragma unroll
    for (int mi = 0; mi < 4; ++mi) {
#pragma unroll
      for (int r = 0; r < 4; ++r) {
        int row = m0 + wr * 64 + mi * 16 + l4 * 4 + r;
        float v = acc[mi][nj][r] + bv;
        if constexpr (F32OUT)
          ((float*)Cout)[(size_t)row * N + col] = v;
        else
          ((unsigned short*)Cout)[(size_t)row * N + col] = f2bf(v);
      }
    }
  }
}

// Batched QKV projection: grid.z selects q/k/v (Wq/bq carry the 1/8 scale).
__global__ __launch_bounds__(256) void gemm_qkv(const unsigned short* __restrict__ Xin,
                                                const unsigned short* __restrict__ Wbf,
                                                const float* __restrict__ bq,
                                                const float* __restrict__ bk,
                                                const float* __restrict__ bv,
                                                unsigned short* __restrict__ Cout) {
  __shared__ unsigned short Al[128 * 64];
  __shared__ unsigned short Bl[128 * 64];
  const int z = blockIdx.z;
  const float* bias = (z == 0) ? bq : (z == 1 ? bk : bv);
  const float bscale = (z == 0) ? 0.125f : 1.0f;
  gemm_bt_tile<false>(Xin + (size_t)z * BT * N_EMBD, Wbf + (size_t)z * N_EMBD * N_EMBD, bias,
                      bscale, Cout + (size_t)z * BT * N_EMBD, blockIdx.x * 128, blockIdx.y * 128,
                      N_EMBD, N_EMBD, Al, Bl);
}

__global__ __launch_bounds__(256) void gemm_out(const unsigned short* __restrict__ Ybf,
                                                const unsigned short* __restrict__ Wo,
                                                const float* __restrict__ bo,
                                                float* __restrict__ Cout) {
  __shared__ unsigned short Al[128 * 64];
  __shared__ unsigned short Bl[128 * 64];
  gemm_bt_tile<true>(Ybf, Wo, bo, 1.0f, Cout, blockIdx.x * 128, blockIdx.y * 128, N_EMBD, N_EMBD,
                     Al, Bl);
}

// ---------------- V transpose: Vp[b,t,h*64+d] -> Vt[(b,h),d,t] ----------------
__global__ __launch_bounds__(256) void transpose_v(const unsigned short* __restrict__ Vp,
                                                   unsigned short* __restrict__ Vt) {
  __shared__ unsigned short tile[64][65];
  const int t0 = blockIdx.x * 64, h = blockIdx.y, b = blockIdx.z;
  const int r = threadIdx.x >> 2, c0 = (threadIdx.x & 3) * 16;
  const unsigned short* src = Vp + (size_t)(b * 1024 + t0 + r) * 1024 + h * 64 + c0;
#pragma unroll
  for (int j = 0; j < 16; ++j) tile[r][c0 + j] = src[j];
  __syncthreads();
  unsigned short* dst = Vt + (size_t)((b * 16 + h) * 64 + r) * 1024 + t0 + c0;
#pragma unroll
  for (int j = 0; j < 16; ++j) dst[j] = tile[c0 + j][r];
}

// ---------------- fused attention ----------------
// Block: 256 threads (4 waves), handles (b, 16 q-rows) x all 16 heads.
// Per head: QK^T (waves split score columns) -> exact softmax (threads own
// [row = tid&15, 64-col chunk = tid>>4]; cross-chunk reduce via LDS) ->
// PV (waves split k, partials reduced in LDS). Head-mean attention
// accumulates in 64 registers/thread, written once at the end.
__global__ __launch_bounds__(256) void attn_fused(const unsigned short* __restrict__ Qp,
                                                  const unsigned short* __restrict__ Kp,
                                                  const unsigned short* __restrict__ Vt,
                                                  unsigned short* __restrict__ Ybf,
                                                  float* __restrict__ attm) {
  __shared__ unsigned short S[16 * 1032];  // scores/probs, bf16, stride 1032 (bank-friendly)
  __shared__ float Yp[4][16 * 64];         // per-wave PV partials
  __shared__ float Red[16 * 16];           // softmax cross-chunk reduce
  __shared__ float invl[16];               // 1/denominator per q-row
  const int tid = threadIdx.x;
  const int l = tid & 63, w = tid >> 6;
  const int l15 = l & 15, l4 = l >> 4;
  const int sr = tid & 15, sg = tid >> 4;  // softmax: row, 64-col chunk
  const int q0 = blockIdx.x * 16, b = blockIdx.y;

  float amean[64];
#pragma unroll
  for (int j = 0; j < 64; ++j) amean[j] = 0.f;

  for (int h = 0; h < NH; ++h) {
    // ---- QK^T: wave w computes score cols [w*256, w*256+256) ----
    const unsigned short* qbase = Qp + (size_t)(b * 1024 + q0 + l15) * 1024 + h * 64 + l4 * 8;
    s16x8 aq0 = *(const s16x8*)qbase;
    s16x8 aq1 = *(const s16x8*)(qbase + 32);
#pragma unroll
    for (int nt = 0; nt < 16; ++nt) {
      int gn = w * 16 + nt;
      const unsigned short* kb = Kp + (size_t)(b * 1024 + gn * 16 + l15) * 1024 + h * 64 + l4 * 8;
      f32x4 sacc = {};
      sacc = __builtin_amdgcn_mfma_f32_16x16x32_bf16(aq0, *(const s16x8*)kb, sacc, 0, 0, 0);
      sacc = __builtin_amdgcn_mfma_f32_16x16x32_bf16(aq1, *(const s16x8*)(kb + 32), sacc, 0, 0, 0);
#pragma unroll
      for (int r = 0; r < 4; ++r) S[(l4 * 4 + r) * 1032 + gn * 16 + l15] = f2bf(sacc[r]);
    }
    __syncthreads();

    // ---- exact softmax ----
    float e[64];
    float m = -1e30f;
#pragma unroll
    for (int jj = 0; jj < 8; ++jj) {
      s16x8 sv = *(const s16x8*)&S[sr * 1032 + sg * 64 + jj * 8];
#pragma unroll
      for (int k2 = 0; k2 < 8; ++k2) {
        float f = bf2f((unsigned short)sv[k2]);
        e[jj * 8 + k2] = f;
        m = fmaxf(m, f);
      }
    }
    Red[sr * 16 + sg] = m;
    __syncthreads();
#pragma unroll
    for (int j = 0; j < 16; ++j) m = fmaxf(m, Red[sr * 16 + j]);
    float psum = 0.f;
#pragma unroll
    for (int j = 0; j < 64; ++j) {
      e[j] = __expf(e[j] - m);
      psum += e[j];
    }
    __syncthreads();
    Red[sr * 16 + sg] = psum;
    __syncthreads();
    float lsum = 0.f;
#pragma unroll
    for (int j = 0; j < 16; ++j) lsum += Red[sr * 16 + j];
    float inv = 1.0f / lsum;
    float inv16 = inv * 0.0625f;
#pragma unroll
    for (int jj = 0; jj < 8; ++jj) {
      s16x8 ev;
#pragma unroll
      for (int k2 = 0; k2 < 8; ++k2) {
        ev[k2] = (short)f2bf(e[jj * 8 + k2]);
        amean[jj * 8 + k2] += e[jj * 8 + k2] * inv16;
      }
      *(s16x8*)&S[sr * 1032 + sg * 64 + jj * 8] = ev;  // un-normalized probs for PV
    }
    if (sg == 0) invl[sr] = inv;
    __syncthreads();

    // ---- P*V: wave w handles k in [w*256, w*256+256) ----
    f32x4 yacc[4] = {};
#pragma unroll
    for (int ks = 0; ks < 8; ++ks) {
      int kb2 = w * 256 + ks * 32 + l4 * 8;
      s16x8 ea = *(const s16x8*)&S[l15 * 1032 + kb2];
#pragma unroll
      for (int nt = 0; nt < 4; ++nt) {
        const unsigned short* vb =
            Vt + (size_t)((b * 16 + h) * 64 + nt * 16 + l15) * 1024 + kb2;
        yacc[nt] = __builtin_amdgcn_mfma_f32_16x16x32_bf16(ea, *(const s16x8*)vb, yacc[nt], 0, 0, 0);
      }
    }
#pragma unroll
    for (int nt = 0; nt < 4; ++nt) {
#pragma unroll
      for (int r = 0; r < 4; ++r) Yp[w][(l4 * 4 + r) * 64 + nt * 16 + l15] = yacc[nt][r];
    }
    __syncthreads();

    // ---- reduce wave partials, apply 1/l, write y (bf16) ----
    {
      int row = tid >> 4, cc = (tid & 15) * 4;
      float iv = invl[row];
#pragma unroll
      for (int j = 0; j < 4; ++j) {
        float s = Yp[0][row * 64 + cc + j] + Yp[1][row * 64 + cc + j] + Yp[2][row * 64 + cc + j] +
                  Yp[3][row * 64 + cc + j];
        Ybf[(size_t)(b * 1024 + q0 + row) * 1024 + h * 64 + cc + j] = f2bf(s * iv);
      }
    }
    __syncthreads();
  }

  // ---- head-mean attention, one write, fp32 ----
  float* ao = attm + (size_t)(b * 1024 + q0 + sr) * 1024 + sg * 64;
#pragma unroll
  for (int jj = 0; jj < 16; ++jj) {
    float4 v = make_float4(amean[jj * 4], amean[jj * 4 + 1], amean[jj * 4 + 2], amean[jj * 4 + 3]);
    *(float4*)(ao + jj * 4) = v;
  }
}

// ---------------------------------------------------------------------------
extern "C" void kernel_launch(void* const* d_in, const int* in_sizes, int n_in, void* d_out,
                              int out_size, void* d_ws, size_t ws_size, hipStream_t stream) {
  const float* q_in = (const float*)d_in[0];
  const float* k_in = (const float*)d_in[1];
  const float* v_in = (const float*)d_in[2];
  const float* Wq = (const float*)d_in[3];
  const float* bq = (const float*)d_in[4];
  const float* Wk = (const float*)d_in[5];
  const float* bk = (const float*)d_in[6];
  const float* Wv = (const float*)d_in[7];
  const float* bv = (const float*)d_in[8];
  const float* Wo = (const float*)d_in[9];
  const float* bo = (const float*)d_in[10];

  float* out_y = (float*)d_out;
  float* out_att = out_y + (size_t)BT * N_EMBD;

  char* ws = (char*)d_ws;
  const size_t MB = 1024 * 1024;
  unsigned short* xin_bf = (unsigned short*)(ws);            // 3 x 8MB (q,k,v inputs bf16)
  unsigned short* W_bf = (unsigned short*)(ws + 24 * MB);    // 4 x 2MB (Wq,Wk,Wv,Wo bf16)
  unsigned short* QKVp = (unsigned short*)(ws + 32 * MB);    // 3 x 8MB (projected Q,K,V)
  unsigned short* Qp = QKVp;
  unsigned short* Kp = QKVp + (size_t)BT * N_EMBD;
  unsigned short* Vp = Kp + (size_t)BT * N_EMBD;
  unsigned short* Vt = (unsigned short*)(ws + 8 * MB);   // reuse k_in slot (dead after proj)
  unsigned short* Ybf = (unsigned short*)(ws + 16 * MB); // reuse v_in slot (dead after proj)

  const int NIN = BT * N_EMBD;       // 4M
  const int NW = N_EMBD * N_EMBD;    // 1M

  cvt_f32_bf16<<<NIN / 1024, 256, 0, stream>>>(q_in, xin_bf, NIN, 1.0f);
  cvt_f32_bf16<<<NIN / 1024, 256, 0, stream>>>(k_in, xin_bf + (size_t)NIN, NIN, 1.0f);
  cvt_f32_bf16<<<NIN / 1024, 256, 0, stream>>>(v_in, xin_bf + (size_t)2 * NIN, NIN, 1.0f);
  cvt_f32_bf16<<<NW / 1024, 256, 0, stream>>>(Wq, W_bf, NW, 0.125f);  // fold 1/sqrt(hd)
  cvt_f32_bf16<<<NW / 1024, 256, 0, stream>>>(Wk, W_bf + (size_t)NW, NW, 1.0f);
  cvt_f32_bf16<<<NW / 1024, 256, 0, stream>>>(Wv, W_bf + (size_t)2 * NW, NW, 1.0f);
  cvt_f32_bf16<<<NW / 1024, 256, 0, stream>>>(Wo, W_bf + (size_t)3 * NW, NW, 1.0f);

  gemm_qkv<<<dim3(BT / 128, N_EMBD / 128, 3), 256, 0, stream>>>(xin_bf, W_bf, bq, bk, bv, QKVp);
  transpose_v<<<dim3(16, 16, 4), 256, 0, stream>>>(Vp, Vt);
  attn_fused<<<dim3(64, 4), 256, 0, stream>>>(Qp, Kp, Vt, Ybf, out_att);
  gemm_out<<<dim3(BT / 128, N_EMBD / 128), 256, 0, stream>>>(Ybf, W_bf + (size_t)3 * NW, bo, out_y);
}

// Round 2
// 252.024 us; speedup vs baseline: 1.2897x; 1.2897x over previous
//
#include <hip/hip_runtime.h>

// ---------------------------------------------------------------------------
// MultiheadAttentionWithAttention: y = Wo(attn(Wq q, Wk k, Wv v)) + bo,
// plus head-mean attention map. B=4, T=T_MEM=1024, C=1024, H=16, hd=64.
//
// Pipeline (bf16 MFMA, fp32 accum):
//   1. convert inputs + weights fp32->bf16 (Wq pre-scaled by 1/8)
//   2. QKV projections: batched 128x128 gemm_bt with global_load_lds staging
//   3. transpose V to [b,h,d,t]
//   4. attn_ph: block = (b, 16 q-rows, 8-head group); per head QK^T ->
//      reg-held softmax -> PV (waves own d-columns); head-mean partial (x1/16)
//      accumulated in regs, one bf16 write per group. XCD-swizzled grid.
//   5. mean2: attm = partial[hg0] + partial[hg1]  (fp32)
//   6. output projection -> fp32 d_out
//
// ws layout (MB), 56 MB total (same as round-1 proven budget):
//   [0,24)  xin bf16 (q,k,v)  -> after gemm_qkv: [0,16) Pmean, [16,24) Vt
//   [24,32) W bf16 in order Wo,Wq,Wk,Wv
//   [32,56) Qp,Kp,Vp          -> Vp slot [48,56) becomes Ybf after transpose
// ---------------------------------------------------------------------------

typedef __attribute__((ext_vector_type(8))) short s16x8;
typedef __attribute__((ext_vector_type(4))) float f32x4;
typedef __attribute__((ext_vector_type(4))) unsigned short u16x4;

#define N_EMBD 1024
#define NH 16
#define BT 4096  // B*T flattened rows
#define STR 1032 // LDS score row stride (elements)

#if __has_builtin(__builtin_amdgcn_global_load_lds)
#define HAVE_GLL 1
#define GLDS16(g, l)                                                              \
  __builtin_amdgcn_global_load_lds((__attribute__((address_space(1))) void*)(g), \
                                   (__attribute__((address_space(3))) void*)(l), 16, 0, 0)
#else
#define HAVE_GLL 0
#endif

static __device__ __forceinline__ unsigned short f2bf(float f) {
  unsigned int u = __builtin_bit_cast(unsigned int, f);
  u += 0x7FFFu + ((u >> 16) & 1u);  // RNE
  return (unsigned short)(u >> 16);
}
static __device__ __forceinline__ float bf2f(unsigned short h) {
  return __builtin_bit_cast(float, ((unsigned int)h) << 16);
}

// ---------------- fp32 -> bf16 convert (optional scale) ----------------
__global__ __launch_bounds__(256) void cvt_f32_bf16(const float* __restrict__ in,
                                                    unsigned short* __restrict__ out,
                                                    int n, float scale) {
  int i = (blockIdx.x * 256 + threadIdx.x) * 4;
  if (i < n) {
    float4 v = *(const float4*)(in + i);
    u16x4 o;
    o[0] = f2bf(v.x * scale);
    o[1] = f2bf(v.y * scale);
    o[2] = f2bf(v.z * scale);
    o[3] = f2bf(v.w * scale);
    *(u16x4*)(out + i) = o;
  }
}

// ---------------- 128x128 bf16 MFMA tile: C = A * B^T + bias ----------------
// A [M,K], B [N,K] row-major bf16. Staging LDS layout is linear in tid*8
// elements (= lane*16 bytes per wave), so global_load_lds width-16 applies.
template <bool F32OUT>
static __device__ __forceinline__ void gemm_bt_tile(const unsigned short* __restrict__ A,
                                                    const unsigned short* __restrict__ B,
                                                    const float* __restrict__ bias, float bscale,
                                                    void* __restrict__ Cout,
                                                    int m0, int n0, int N, int K,
                                                    unsigned short* Al, unsigned short* Bl) {
  const int tid = threadIdx.x;
  const int l = tid & 63, w = tid >> 6;
  const int wr = w >> 1, wc = w & 1;
  const int l15 = l & 15, l4 = l >> 4;
  const int srow = tid >> 3;          // staging row within 32-row chunk
  const int skk = (tid & 7) * 8;      // staging k offset (16B)
  f32x4 acc[4][4] = {};
  for (int k0 = 0; k0 < K; k0 += 64) {
#if HAVE_GLL
#pragma unroll
    for (int i = 0; i < 4; ++i) {
      GLDS16(&A[(size_t)(m0 + i * 32 + srow) * K + k0 + skk], Al + i * 2048 + w * 512);
      GLDS16(&B[(size_t)(n0 + i * 32 + srow) * K + k0 + skk], Bl + i * 2048 + w * 512);
    }
#else
#pragma unroll
    for (int i = 0; i < 4; ++i) {
      int row = i * 32 + srow;
      *(s16x8*)&Al[row * 64 + skk] = *(const s16x8*)&A[(size_t)(m0 + row) * K + k0 + skk];
      *(s16x8*)&Bl[row * 64 + skk] = *(const s16x8*)&B[(size_t)(n0 + row) * K + k0 + skk];
    }
#endif
    __syncthreads();
#pragma unroll
    for (int kf = 0; kf < 2; ++kf) {
      s16x8 af[4], bfr[4];
#pragma unroll
      for (int mi = 0; mi < 4; ++mi)
        af[mi] = *(const s16x8*)&Al[(wr * 64 + mi * 16 + l15) * 64 + kf * 32 + l4 * 8];
#pragma unroll
      for (int nj = 0; nj < 4; ++nj)
        bfr[nj] = *(const s16x8*)&Bl[(wc * 64 + nj * 16 + l15) * 64 + kf * 32 + l4 * 8];
#pragma unroll
      for (int mi = 0; mi < 4; ++mi) {
#pragma unroll
        for (int nj = 0; nj < 4; ++nj)
          acc[mi][nj] =
              __builtin_amdgcn_mfma_f32_16x16x32_bf16(af[mi], bfr[nj], acc[mi][nj], 0, 0, 0);
      }
    }
    __syncthreads();
  }
#pragma unroll
  for (int nj = 0; nj < 4; ++nj) {
    int col = n0 + wc * 64 + nj * 16 + l15;
    float bv = bias[col] * bscale;
#pragma unroll
    for (int mi = 0; mi < 4; ++mi) {
#pragma unroll
      for (int r = 0; r < 4; ++r) {
        int row = m0 + wr * 64 + mi * 16 + l4 * 4 + r;
        float v = acc[mi][nj][r] + bv;
        if constexpr (F32OUT)
          ((float*)Cout)[(size_t)row * N + col] = v;
        else
          ((unsigned short*)Cout)[(size_t)row * N + col] = f2bf(v);
      }
    }
  }
}

// Batched QKV projection: grid.z selects q/k/v. Weights ordered Wo,Wq,Wk,Wv.
__global__ __launch_bounds__(256) void gemm_qkv(const unsigned short* __restrict__ Xin,
                                                const unsigned short* __restrict__ Wbf,
                                                const float* __restrict__ bq,
                                                const float* __restrict__ bk,
                                                const float* __restrict__ bv,
                                                unsigned short* __restrict__ Cout) {
  __shared__ unsigned short Al[128 * 64];
  __shared__ unsigned short Bl[128 * 64];
  const int z = blockIdx.z;
  const float* bias = (z == 0) ? bq : (z == 1 ? bk : bv);
  const float bscale = (z == 0) ? 0.125f : 1.0f;
  gemm_bt_tile<false>(Xin + (size_t)z * BT * N_EMBD,
                      Wbf + (size_t)(1 + z) * N_EMBD * N_EMBD, bias, bscale,
                      Cout + (size_t)z * BT * N_EMBD, blockIdx.x * 128, blockIdx.y * 128,
                      N_EMBD, N_EMBD, Al, Bl);
}

__global__ __launch_bounds__(256) void gemm_out(const unsigned short* __restrict__ Ybf,
                                                const unsigned short* __restrict__ Wo,
                                                const float* __restrict__ bo,
                                                float* __restrict__ Cout) {
  __shared__ unsigned short Al[128 * 64];
  __shared__ unsigned short Bl[128 * 64];
  gemm_bt_tile<true>(Ybf, Wo, bo, 1.0f, Cout, blockIdx.x * 128, blockIdx.y * 128, N_EMBD, N_EMBD,
                     Al, Bl);
}

// ---------------- V transpose: Vp[b,t,h*64+d] -> Vt[(b,h),d,t] ----------------
__global__ __launch_bounds__(256) void transpose_v(const unsigned short* __restrict__ Vp,
                                                   unsigned short* __restrict__ Vt) {
  __shared__ unsigned short tile[64][65];
  const int t0 = blockIdx.x * 64, h = blockIdx.y, b = blockIdx.z;
  const int r = threadIdx.x >> 2, c0 = (threadIdx.x & 3) * 16;
  const unsigned short* src = Vp + (size_t)(b * 1024 + t0 + r) * 1024 + h * 64 + c0;
#pragma unroll
  for (int j = 0; j < 16; ++j) tile[r][c0 + j] = src[j];
  __syncthreads();
  unsigned short* dst = Vt + (size_t)((b * 16 + h) * 64 + r) * 1024 + t0 + c0;
#pragma unroll
  for (int j = 0; j < 16; ++j) dst[j] = tile[c0 + j][r];
}

// ---------------- fused attention, head-group partial ----------------
// Block: 256 threads (4 waves) = (b, 16 q-rows, head group hg of 8 heads).
// Grid flat 512, XCD-bijective swizzle: XCD x owns (b,hg) = x, so its
// 8-head K/V working set (2 MB) stays resident in its private L2.
// Per head: QK^T (wave w -> score cols [w*256,w*256+256)), softmax with
// scores held in registers across passes (RedM/RedS double buffers),
// PV (wave w -> d cols [w*16,w*16+16), full K, no cross-wave reduce).
// Head-mean partial (sum p/16 over the 8 heads) kept in 64 regs/thread,
// written once as bf16.
__global__ __launch_bounds__(256) void attn_ph(const unsigned short* __restrict__ Qp,
                                               const unsigned short* __restrict__ Kp,
                                               const unsigned short* __restrict__ Vt,
                                               unsigned short* __restrict__ Ybf,
                                               unsigned short* __restrict__ Pmean) {
  __shared__ unsigned short S[16 * STR];  // scores/probs bf16
  __shared__ float RedM[16][16];
  __shared__ float RedS[16][16];
  __shared__ float invl[16];
  const int tid = threadIdx.x;
  const int l = tid & 63, w = tid >> 6;
  const int l15 = l & 15, l4 = l >> 4;
  const int r = tid & 15, c = tid >> 4;  // softmax: row, 16-col-group owner

  int bid = blockIdx.x;
  int swz = (bid & 7) * 64 + (bid >> 3);  // 512 = 8 XCD chunks of 64
  int qt = swz & 63;
  int grp = swz >> 6;          // 0..7 = b*2+hg -> one per XCD
  int b = grp >> 1, hg = grp & 1;
  int q0 = qt * 16;

  float amean[64];
#pragma unroll
  for (int j = 0; j < 64; ++j) amean[j] = 0.f;

#pragma unroll 1
  for (int hh = 0; hh < 8; ++hh) {
    const int h = hg * 8 + hh;
    // ---- QK^T ----
    const unsigned short* qbase = Qp + (size_t)(b * 1024 + q0 + l15) * 1024 + h * 64 + l4 * 8;
    s16x8 aq0 = *(const s16x8*)qbase;
    s16x8 aq1 = *(const s16x8*)(qbase + 32);
#pragma unroll
    for (int nt = 0; nt < 16; ++nt) {
      int gn = w * 16 + nt;
      const unsigned short* kb = Kp + (size_t)(b * 1024 + gn * 16 + l15) * 1024 + h * 64 + l4 * 8;
      f32x4 sacc = {};
      sacc = __builtin_amdgcn_mfma_f32_16x16x32_bf16(aq0, *(const s16x8*)kb, sacc, 0, 0, 0);
      sacc = __builtin_amdgcn_mfma_f32_16x16x32_bf16(aq1, *(const s16x8*)(kb + 32), sacc, 0, 0, 0);
#pragma unroll
      for (int rr = 0; rr < 4; ++rr) S[(l4 * 4 + rr) * STR + gn * 16 + l15] = f2bf(sacc[rr]);
    }
    __syncthreads();  // A: scores visible

    // ---- softmax: thread (r,c) owns cols c*16 + kt*256 + {0..15} ----
    float ev[64];
    float m = -3.4e38f;
#pragma unroll
    for (int k = 0; k < 8; ++k) {
      s16x8 sv = *(const s16x8*)&S[r * STR + c * 16 + (k >> 1) * 256 + (k & 1) * 8];
#pragma unroll
      for (int j = 0; j < 8; ++j) {
        float f = bf2f((unsigned short)sv[j]);
        ev[k * 8 + j] = f;
        m = fmaxf(m, f);
      }
    }
    RedM[r][c] = m;
    __syncthreads();  // B
#pragma unroll
    for (int j = 0; j < 16; ++j) m = fmaxf(m, RedM[r][j]);
    float ps = 0.f;
#pragma unroll
    for (int j = 0; j < 64; ++j) {
      ev[j] = __expf(ev[j] - m);
      ps += ev[j];
    }
    RedS[r][c] = ps;
    // write back unnormalized probs (bf16) for PV
#pragma unroll
    for (int k = 0; k < 8; ++k) {
      s16x8 evv;
#pragma unroll
      for (int j = 0; j < 8; ++j) evv[j] = (short)f2bf(ev[k * 8 + j]);
      *(s16x8*)&S[r * STR + c * 16 + (k >> 1) * 256 + (k & 1) * 8] = evv;
    }
    __syncthreads();  // C: RedS + prob writeback visible
    float ls = 0.f;
#pragma unroll
    for (int j = 0; j < 16; ++j) ls += RedS[r][j];
    float inv = 1.0f / ls;
    if (c == 0) invl[r] = inv;
    float sc = inv * 0.0625f;
#pragma unroll
    for (int j = 0; j < 64; ++j) amean[j] += ev[j] * sc;
    __syncthreads();  // D: invl visible

    // ---- P*V: wave w owns d cols [w*16, w*16+16) ----
    f32x4 y = {};
    const unsigned short* vb = Vt + (size_t)((b * 16 + h) * 64 + w * 16 + l15) * 1024 + l4 * 8;
#pragma unroll
    for (int ks = 0; ks < 32; ++ks) {
      s16x8 pa = *(const s16x8*)&S[l15 * STR + ks * 32 + l4 * 8];
      y = __builtin_amdgcn_mfma_f32_16x16x32_bf16(pa, *(const s16x8*)(vb + ks * 32), y, 0, 0, 0);
    }
#pragma unroll
    for (int rr = 0; rr < 4; ++rr) {
      int row = l4 * 4 + rr;
      Ybf[(size_t)(b * 1024 + q0 + row) * 1024 + h * 64 + w * 16 + l15] = f2bf(y[rr] * invl[row]);
    }
    __syncthreads();  // E: S/invl reuse next head
  }

  // ---- head-group partial mean (already scaled by 1/16), bf16, one write ----
  unsigned short* pm = Pmean + (size_t)((b * 2 + hg) * 1024 + q0 + r) * 1024 + c * 16;
#pragma unroll
  for (int k = 0; k < 8; ++k) {
    s16x8 ov;
#pragma unroll
    for (int j = 0; j < 8; ++j) ov[j] = (short)f2bf(amean[k * 8 + j]);
    *(s16x8*)&pm[(k >> 1) * 256 + (k & 1) * 8] = ov;
  }
}

// ---------------- attm = partial[hg0] + partial[hg1] (fp32 out) ----------------
__global__ __launch_bounds__(256) void mean2(const unsigned short* __restrict__ P2,
                                             float* __restrict__ out) {
  size_t f = ((size_t)blockIdx.x * 256 + threadIdx.x) * 8;
  int b = (int)(f >> 20);
  size_t i0 = f + ((size_t)b << 20);
  s16x8 a = *(const s16x8*)&P2[i0];
  s16x8 d = *(const s16x8*)&P2[i0 + (1u << 20)];
  float4 o0, o1;
  o0.x = bf2f((unsigned short)a[0]) + bf2f((unsigned short)d[0]);
  o0.y = bf2f((unsigned short)a[1]) + bf2f((unsigned short)d[1]);
  o0.z = bf2f((unsigned short)a[2]) + bf2f((unsigned short)d[2]);
  o0.w = bf2f((unsigned short)a[3]) + bf2f((unsigned short)d[3]);
  o1.x = bf2f((unsigned short)a[4]) + bf2f((unsigned short)d[4]);
  o1.y = bf2f((unsigned short)a[5]) + bf2f((unsigned short)d[5]);
  o1.z = bf2f((unsigned short)a[6]) + bf2f((unsigned short)d[6]);
  o1.w = bf2f((unsigned short)a[7]) + bf2f((unsigned short)d[7]);
  *(float4*)&out[f] = o0;
  *(float4*)&out[f + 4] = o1;
}

// ---------------------------------------------------------------------------
extern "C" void kernel_launch(void* const* d_in, const int* in_sizes, int n_in, void* d_out,
                              int out_size, void* d_ws, size_t ws_size, hipStream_t stream) {
  const float* q_in = (const float*)d_in[0];
  const float* k_in = (const float*)d_in[1];
  const float* v_in = (const float*)d_in[2];
  const float* Wq = (const float*)d_in[3];
  const float* bq = (const float*)d_in[4];
  const float* Wk = (const float*)d_in[5];
  const float* bk = (const float*)d_in[6];
  const float* Wv = (const float*)d_in[7];
  const float* bv = (const float*)d_in[8];
  const float* Wo = (const float*)d_in[9];
  const float* bo = (const float*)d_in[10];

  float* out_y = (float*)d_out;
  float* out_att = out_y + (size_t)BT * N_EMBD;

  char* ws = (char*)d_ws;
  const size_t MB = 1024 * 1024;
  unsigned short* xin_bf = (unsigned short*)(ws);           // 3 x 8MB (q,k,v inputs bf16)
  unsigned short* W_bf = (unsigned short*)(ws + 24 * MB);   // Wo,Wq,Wk,Wv bf16
  unsigned short* Qp = (unsigned short*)(ws + 32 * MB);
  unsigned short* Kp = Qp + (size_t)BT * N_EMBD;
  unsigned short* Vp = Kp + (size_t)BT * N_EMBD;
  unsigned short* Pmean = (unsigned short*)(ws);            // [b][2][1024][1024] (16MB, over dead q/k xin)
  unsigned short* Vt = (unsigned short*)(ws + 16 * MB);     // over dead v xin
  unsigned short* Ybf = Vp;                                 // over dead Vp (after transpose_v)

  const int NIN = BT * N_EMBD;     // 4M
  const int NW = N_EMBD * N_EMBD;  // 1M

  cvt_f32_bf16<<<NIN / 1024, 256, 0, stream>>>(q_in, xin_bf, NIN, 1.0f);
  cvt_f32_bf16<<<NIN / 1024, 256, 0, stream>>>(k_in, xin_bf + (size_t)NIN, NIN, 1.0f);
  cvt_f32_bf16<<<NIN / 1024, 256, 0, stream>>>(v_in, xin_bf + (size_t)2 * NIN, NIN, 1.0f);
  cvt_f32_bf16<<<NW / 1024, 256, 0, stream>>>(Wo, W_bf, NW, 1.0f);
  cvt_f32_bf16<<<NW / 1024, 256, 0, stream>>>(Wq, W_bf + (size_t)NW, NW, 0.125f);  // fold 1/sqrt(hd)
  cvt_f32_bf16<<<NW / 1024, 256, 0, stream>>>(Wk, W_bf + (size_t)2 * NW, NW, 1.0f);
  cvt_f32_bf16<<<NW / 1024, 256, 0, stream>>>(Wv, W_bf + (size_t)3 * NW, NW, 1.0f);

  gemm_qkv<<<dim3(BT / 128, N_EMBD / 128, 3), 256, 0, stream>>>(xin_bf, W_bf, bq, bk, bv, Qp);
  transpose_v<<<dim3(16, 16, 4), 256, 0, stream>>>(Vp, Vt);
  attn_ph<<<512, 256, 0, stream>>>(Qp, Kp, Vt, Ybf, Pmean);
  mean2<<<2048, 256, 0, stream>>>(Pmean, out_att);
  gemm_out<<<dim3(BT / 128, N_EMBD / 128), 256, 0, stream>>>(Ybf, W_bf, bo, out_y);
}